// Round 3
// baseline (12.820 us; speedup 1.0000x reference)
//
#include <hip/hip_runtime.h>
#include <math.h>

constexpr int B_ = 4, L_ = 2048, K_ = 64, T_ = 1000;
constexpr int CHUNKS = 4;                 // split each row of L into 4 chunks
constexpr int CHUNK_LEN = L_ / CHUNKS;    // 512 positions per block
#define EPSF 1e-6f

__device__ __forceinline__ float wave_sum64(float v) {
#pragma unroll
    for (int o = 32; o; o >>= 1) v += __shfl_xor(v, o, 64);
    return v;
}

// log((1-w)*exp(a) + w*exp(b)) with boundary handling; w is wave-uniform.
__device__ __forceinline__ float mix_logits(float a, float b, float w) {
    if (w < 1e-6f) return a;
    if (w > 1.0f - 1e-6f) return b;
    float ws = fminf(fmaxf(w, 1e-6f), 1.0f - 1e-6f);
    float x = a + logf(1.0f - ws), y = b + logf(ws);
    float m = fmaxf(x, y);
    return m + log1pf(expf(fminf(x, y) - m));
}

// Softmax prob u[lane] of the mixed marginal logits for time tt (wave-uniform).
// Max-subtraction dropped: |raw| <= ~8 so exp is safe in fp32, and the final
// logits are <= log(2) so the second exp is safe too.
__device__ __forceinline__ float get_u(int lane, float we,
                                       const float* __restrict__ W_t,
                                       int tt, int x0) {
    float raw = we + W_t[tt * K_ + lane];
    float log_net = raw - logf(wave_sum64(expf(raw)));

    float tn = (float)tt / (float)T_;
    float cr = 2.0f * tn - 1.0f;
    cr *= cr;

    float x0lp = (lane == x0) ? logf(1.0f + EPSF) : logf(EPSF);
    const float uniflp = logf(1.0f / (float)K_);

    float control = mix_logits(x0lp, uniflp, tn);
    float logit = mix_logits(log_net, control, cr);

    float e = expf(logit);
    float s = wave_sum64(e);
    return e / s;
}

// One wave per (b, x0, chunk). The wave computes the coupling tables for its
// (t[b], x0) combo in registers, then scans x_0[b, chunk] and writes output
// rows for every position whose x_0 matches. Each position matches exactly
// one x0, so every output row is written exactly once.
__global__ __launch_bounds__(64) void fldd_one(
        const float* __restrict__ W_emb,
        const float* __restrict__ W_t,
        const int* __restrict__ x_0,
        const int* __restrict__ x_t,
        const int* __restrict__ t,
        float* __restrict__ out) {
    const int lane = threadIdx.x;
    const int blk = blockIdx.x;
    const int c = blk >> 2;            // combo id in [0, 256)
    const int chunk = blk & (CHUNKS - 1);
    const int b = c >> 6;
    const int x0 = c & 63;
    const int tb = t[b];

    const float we = W_emb[x0 * K_ + lane];
    const float u_t = get_u(lane, we, W_t, tb, x0);
    const float u_s = get_u(lane, we, W_t, tb - 1, x0);

    const float diff = fmaxf(u_s - u_t, 0.0f);
    const float D = wave_sum64(diff);
    const float mst = diff / (D + EPSF);
    const float S = D / (D + EPSF);                     // sum_k m_st
    const float a  = fminf(u_s, u_t) / (u_t + EPSF);    // prob_stay(j = lane)
    const float pm = fmaxf(u_t - u_s, 0.0f) / (u_t + EPSF); // prob_move(j)
    const float rd = 1.0f / (a + pm * S + EPSF);        // 1/denom(j)

    const int base = b * L_ + chunk * CHUNK_LEN;
#pragma unroll
    for (int it = 0; it < CHUNK_LEN / 64; ++it) {
        const int p = base + it * 64 + lane;
        const int x0v = x_0[p];
        const int xtv = x_t[p];
        unsigned long long mask = __ballot(x0v == x0);
        while (mask) {
            const int j = (int)__builtin_ctzll(mask);
            mask &= mask - 1;
            const int pp = base + it * 64 + j;
            const int xt  = __shfl(xtv, j, 64);
            const float aj  = __shfl(a,  xt, 64);
            const float pmj = __shfl(pm, xt, 64);
            const float rdj = __shfl(rd, xt, 64);
            const float q = ((lane == xt) ? aj : 0.0f) + pmj * mst;
            out[pp * K_ + lane] = logf(fmaf(q, rdj, EPSF));
        }
    }
}

extern "C" void kernel_launch(void* const* d_in, const int* in_sizes, int n_in,
                              void* d_out, int out_size, void* d_ws, size_t ws_size,
                              hipStream_t stream) {
    const float* W_emb = (const float*)d_in[0];
    const float* W_t   = (const float*)d_in[1];
    const int*   x_0   = (const int*)d_in[2];
    const int*   x_t   = (const int*)d_in[3];
    const int*   t     = (const int*)d_in[4];
    float* out = (float*)d_out;

    const int blocks = B_ * K_ * CHUNKS;   // 1024 blocks, 1 wave each
    fldd_one<<<blocks, 64, 0, stream>>>(W_emb, W_t, x_0, x_t, t, out);
}

// Round 4
// 9.719 us; speedup vs baseline: 1.3191x; 1.3191x over previous
//
#include <hip/hip_runtime.h>
#include <math.h>

constexpr int B_ = 4, L_ = 2048, K_ = 64, T_ = 1000;
constexpr int CHUNKS = 16;                 // blocks per (b,x0) combo
constexpr int CHUNK_LEN = L_ / CHUNKS;     // 128 positions per block (2 iters of 64)
#define EPSF 1e-6f

__device__ __forceinline__ float wave_sum64(float v) {
#pragma unroll
    for (int o = 32; o; o >>= 1) v += __shfl_xor(v, o, 64);
    return v;
}

// Softmax prob u[lane] of the mixed marginal logits, computed entirely in
// probability space:
//   p_net  = softmax(raw)
//   p_ctrl = (1-tn)*(onehot+EPS) + tn/K            (exp of control_lp, closed form)
//   pu     = (1-cr)*p_net + cr*p_ctrl              (exp of mixed logits)
//   u      = pu / sum(pu), where sum(pu) has the closed form
//            (1-cr) + cr*(1 + (1-tn)*64*EPS)       (p_net already normalized)
// Boundary cases (w<1e-6 / w>1-1e-6) follow the reference's jnp.where exactly.
__device__ __forceinline__ float get_u(int lane, float we,
                                       const float* __restrict__ W_t,
                                       int tt, int x0) {
    float raw = we + W_t[tt * K_ + lane];   // |raw| <= ~10, exp safe in fp32
    float e = expf(raw);
    float pnet = e / wave_sum64(e);

    float tn = (float)tt / (float)T_;
    float cr = 2.0f * tn - 1.0f;
    cr *= cr;

    const float onehot = (lane == x0) ? 1.0f + EPSF : EPSF;

    float pctrl, sumc;
    if (tn < 1e-6f) {                       // control = x0 log-probs exactly
        pctrl = onehot;
        sumc = 1.0f + 64.0f * EPSF;
    } else if (tn > 1.0f - 1e-6f) {         // control = uniform exactly
        pctrl = 1.0f / (float)K_;
        sumc = 1.0f;
    } else {                                // tn already inside clip range
        pctrl = (1.0f - tn) * onehot + tn * (1.0f / (float)K_);
        sumc = 1.0f + (1.0f - tn) * 64.0f * EPSF;
    }

    if (cr < 1e-6f) return pnet;
    if (cr > 1.0f - 1e-6f) return pctrl / sumc;
    float pu = (1.0f - cr) * pnet + cr * pctrl;
    float st = (1.0f - cr) + cr * sumc;
    return pu / st;
}

// One wave per (b, x0, chunk). Wave computes the coupling tables for its
// (t[b], x0) combo in registers, then scans its chunk of x_0[b,:] and writes
// output rows for matching positions (each position matches exactly one x0).
__global__ __launch_bounds__(64) void fldd_one(
        const float* __restrict__ W_emb,
        const float* __restrict__ W_t,
        const int* __restrict__ x_0,
        const int* __restrict__ x_t,
        const int* __restrict__ t,
        float* __restrict__ out) {
    const int lane = threadIdx.x;
    const int blk = blockIdx.x;
    const int c = blk >> 4;                 // combo id in [0, 256)
    const int chunk = blk & (CHUNKS - 1);
    const int b = c >> 6;
    const int x0 = c & 63;

    // Prefetch scan inputs so their latency hides under the combo chain.
    const int base = b * L_ + chunk * CHUNK_LEN;
    const int x0v0 = x_0[base + lane];
    const int xtv0 = x_t[base + lane];
    const int x0v1 = x_0[base + 64 + lane];
    const int xtv1 = x_t[base + 64 + lane];
    const int tb = t[b];

    const float we = W_emb[x0 * K_ + lane];
    const float u_t = get_u(lane, we, W_t, tb, x0);
    const float u_s = get_u(lane, we, W_t, tb - 1, x0);

    const float diff = fmaxf(u_s - u_t, 0.0f);
    const float D = wave_sum64(diff);
    const float mst = diff / (D + EPSF);
    const float S = D / (D + EPSF);                       // sum_k m_st
    const float a  = fminf(u_s, u_t) / (u_t + EPSF);      // prob_stay(j = lane)
    const float pm = fmaxf(u_t - u_s, 0.0f) / (u_t + EPSF); // prob_move(j)
    const float rd = 1.0f / (a + pm * S + EPSF);          // 1/denom(j)

#pragma unroll
    for (int it = 0; it < 2; ++it) {
        const int x0v = it ? x0v1 : x0v0;
        const int xtv = it ? xtv1 : xtv0;
        unsigned long long mask = __ballot(x0v == x0);
        while (mask) {
            const int j = (int)__builtin_ctzll(mask);
            mask &= mask - 1;
            const int pp = base + it * 64 + j;
            const int xt  = __shfl(xtv, j, 64);
            const float aj  = __shfl(a,  xt, 64);
            const float pmj = __shfl(pm, xt, 64);
            const float rdj = __shfl(rd, xt, 64);
            const float q = ((lane == xt) ? aj : 0.0f) + pmj * mst;
            out[pp * K_ + lane] = logf(fmaf(q, rdj, EPSF));
        }
    }
}

extern "C" void kernel_launch(void* const* d_in, const int* in_sizes, int n_in,
                              void* d_out, int out_size, void* d_ws, size_t ws_size,
                              hipStream_t stream) {
    const float* W_emb = (const float*)d_in[0];
    const float* W_t   = (const float*)d_in[1];
    const int*   x_0   = (const int*)d_in[2];
    const int*   x_t   = (const int*)d_in[3];
    const int*   t     = (const int*)d_in[4];
    float* out = (float*)d_out;

    const int blocks = B_ * K_ * CHUNKS;    // 4096 blocks, 1 wave each
    fldd_one<<<blocks, 64, 0, stream>>>(W_emb, W_t, x_0, x_t, t, out);
}